// Round 13
// baseline (106.598 us; speedup 1.0000x reference)
//
#include <hip/hip_runtime.h>

#define B_   8
#define N_   307
#define BN   (B_ * N_)          // 2456 bn tiles
#define NB2  (BN / 2)           // 1228 blocks, 2 tiles each
#define OUT_ELEMS (BN * 64 * 64)

typedef float f32x4 __attribute__((ext_vector_type(4)));
typedef short s16x8 __attribute__((ext_vector_type(8)));

__device__ __forceinline__ unsigned short f2bf(float x) {
    unsigned int u = __builtin_bit_cast(unsigned int, x);
    u += 0x7FFFu + ((u >> 16) & 1u);        // round-to-nearest-even
    return (unsigned short)(u >> 16);
}

// LDS-only barrier: all barriers here exist for LDS visibility only (no wave
// reads another wave's global writes; global loads are consumed by the issuing
// wave with compiler-inserted data-dep waits). lgkmcnt-only -> in-flight
// global loads/stores survive across phase boundaries.
__device__ __forceinline__ void bar_lds() {
    asm volatile("s_waitcnt lgkmcnt(0)\n\ts_barrier" ::: "memory");
}

// XOR-swizzle on 16B frag rows (G4 / m201): bijective within 8-row groups.
__device__ __forceinline__ int swz(int row) { return row ^ ((row >> 3) & 7); }

__device__ __forceinline__ s16x8 ldfrag(const unsigned short* p) {
    return *reinterpret_cast<const s16x8*>(p);
}

__device__ __forceinline__ s16x8 cvt8(float4 lo, float4 hi) {
    s16x8 f;
    f[0] = (short)f2bf(lo.x); f[1] = (short)f2bf(lo.y);
    f[2] = (short)f2bf(lo.z); f[3] = (short)f2bf(lo.w);
    f[4] = (short)f2bf(hi.x); f[5] = (short)f2bf(hi.y);
    f[6] = (short)f2bf(hi.z); f[7] = (short)f2bf(hi.w);
    return f;
}

__device__ __forceinline__ void loadW(const float* __restrict__ src,
                                      float4 wvv[4], int tid) {
    const float4* s4 = reinterpret_cast<const float4*>(src);
#pragma unroll
    for (int i = 0; i < 4; ++i) wvv[i] = s4[i * 256 + tid];
}

// regs (64x64 row-major fp32 K x N) -> bf16 B-operand frag layout (swizzled)
__device__ __forceinline__ void writeW(const float4 wvv[4],
                                       unsigned short* dst, int tid) {
#pragma unroll
    for (int i = 0; i < 4; ++i) {
        int idx = i * 256 + tid;
        float4 v = wvv[i];
        int k  = idx >> 4;
        int n0 = (idx & 15) << 2;
        int ki = k >> 5;
        int qd = (k >> 3) & 3;
        int j  = k & 7;
        float vv[4] = {v.x, v.y, v.z, v.w};
#pragma unroll
        for (int c = 0; c < 4; ++c) {
            int n = n0 + c;
            int row = ((n >> 4) * 2 + ki) * 64 + (qd << 4) + (n & 15);
            dst[(swz(row) << 3) + j] = f2bf(vv[c]);
        }
    }
}

// per-tile projection: X A-frags (regs) x W B-frags (LDS) -> Q/K/V frag stores
template <int PJ>
__device__ __forceinline__ void proj_tile(const float4 xv[4],
                                          const unsigned short* wbuf,
                                          unsigned short* sQf, unsigned short* sKf,
                                          unsigned short* sVf,
                                          int w, int lane, int quad, int l16)
{
    s16x8 a0 = cvt8(xv[0], xv[1]);
    s16x8 a1 = cvt8(xv[2], xv[3]);
#pragma unroll
    for (int nt = 0; nt < 4; ++nt) {
        f32x4 acc = {0.f, 0.f, 0.f, 0.f};
        s16x8 b0 = ldfrag(wbuf + (swz((nt * 2 + 0) * 64 + lane) << 3));
        s16x8 b1 = ldfrag(wbuf + (swz((nt * 2 + 1) * 64 + lane) << 3));
        acc = __builtin_amdgcn_mfma_f32_16x16x32_bf16(a0, b0, acc, 0, 0, 0);
        acc = __builtin_amdgcn_mfma_f32_16x16x32_bf16(a1, b1, acc, 0, 0, 0);
        if (PJ == 0) {              // Q -> B-frag layout, fold 1/sqrt(16)
#pragma unroll
            for (int r = 0; r < 4; ++r) {
                int rowq = (nt * 4 + w) * 32 + ((l16 >> 3) << 4) + quad * 4 + r;
                sQf[(swz(rowq) << 3) + (l16 & 7)] = f2bf(acc[r] * 0.25f);
            }
        } else if (PJ == 1) {       // K -> B-frag layout
#pragma unroll
            for (int r = 0; r < 4; ++r) {
                int rowk = (nt * 4 + w) * 32 + ((l16 >> 3) << 4) + quad * 4 + r;
                sKf[(swz(rowk) << 3) + (l16 & 7)] = f2bf(acc[r]);
            }
        } else {                    // V -> PV B-frag layout (nt == head)
#pragma unroll
            for (int r = 0; r < 4; ++r) {
                int kk = w * 16 + quad * 4 + r;
                int rowv = (nt * 2 + (kk >> 5)) * 64 + (((kk >> 3) & 3) << 4) + l16;
                sVf[(swz(rowv) << 3) + (kk & 7)] = f2bf(acc[r]);
            }
        }
    }
}

// one tile's S^T + softmax + frag writes + score stores for head h (R10 math)
__device__ __forceinline__ void attn_tile(const unsigned short* sKf,
                                          const unsigned short* sQf,
                                          unsigned short* buf,
                                          const f32x4 rA[4], const bool bmv[4],
                                          float* __restrict__ sp, int h,
                                          int w, int lane, int quad, int l16)
{
    const s16x8 zf = {0, 0, 0, 0, 0, 0, 0, 0};
    s16x8 bk = zf;
    if (lane < 32) bk = ldfrag(sKf + (swz((h * 4 + w) * 32 + lane) << 3));
    f32x4 sr[4];
    float esum[4] = {0.f, 0.f, 0.f, 0.f};
#pragma unroll
    for (int nt = 0; nt < 4; ++nt) {
        s16x8 aq = zf;
        if (lane < 32) aq = ldfrag(sQf + (swz((h * 4 + nt) * 32 + lane) << 3));
        f32x4 t = __builtin_amdgcn_mfma_f32_16x16x32_bf16(bk, aq, rA[nt], 0, 0, 0);
#pragma unroll
        for (int r = 0; r < 4; ++r) {
            float s = bmv[nt] ? -1e9f : t[r];
            sr[nt][r] = s;
            esum[r] += __expf(s);   // masked -> underflows to +0
        }
    }
#pragma unroll
    for (int m = 1; m <= 8; m <<= 1)
#pragma unroll
        for (int r = 0; r < 4; ++r)
            esum[r] += __shfl_xor(esum[r], m, 64);
    float inv[4];
#pragma unroll
    for (int r = 0; r < 4; ++r) inv[r] = 1.0f / (esum[r] + 1e-30f);
    // attn -> PV A-frag layout: one short4 per q-tile (4 consecutive j)
#pragma unroll
    for (int nt = 0; nt < 4; ++nt) {
        int row = (nt * 2 + (w >> 1)) * 64 + (((w & 1) << 1) + (quad >> 1)) * 16 + l16;
        short4 pk;
        pk.x = (short)f2bf(__expf(sr[nt][0]) * inv[0]);
        pk.y = (short)f2bf(__expf(sr[nt][1]) * inv[1]);
        pk.z = (short)f2bf(__expf(sr[nt][2]) * inv[2]);
        pk.w = (short)f2bf(__expf(sr[nt][3]) * inv[3]);
        *reinterpret_cast<short4*>(buf + (swz(row) << 3) + ((quad & 1) << 2)) = pk;
    }
    // masked-score stores: float4, survive the lgkm-only barrier
#pragma unroll
    for (int nt = 0; nt < 4; ++nt)
        *reinterpret_cast<f32x4*>(sp + nt * 1024) = sr[nt];
}

__global__ __launch_bounds__(256, 2) void mta_kernel(
    const float* __restrict__ Xq, const float* __restrict__ Xk,
    const float* __restrict__ Xv, const float* __restrict__ maskp,
    const float* __restrict__ res, const float* __restrict__ Wq,
    const float* __restrict__ Wk, const float* __restrict__ Wv,
    const float* __restrict__ Wfc, const float* __restrict__ lnS,
    const float* __restrict__ lnB, float* __restrict__ out,
    float* __restrict__ scores_out)
{
    // TWO bn tiles per block (dual-stream ILP): tile-B's independent chain
    // hides tile-A's latency inside each wave. Barriers + W staging per tile
    // halve. 80KB LDS -> 2 blocks/CU; (256,2) -> VGPR cap 256 (no spill).
    __shared__ __align__(16) unsigned char smem[81920];
    unsigned short* sKf0 = (unsigned short*)(smem);           // tile A: K / ctx (fc)
    unsigned short* sQf0 = (unsigned short*)(smem + 8192);    // tile A: Q
    unsigned short* sVf0 = (unsigned short*)(smem + 16384);   // tile A: V
    unsigned short* sKf1 = (unsigned short*)(smem + 24576);   // tile B: K / ctx (fc)
    unsigned short* sQf1 = (unsigned short*)(smem + 32768);   // tile B: Q
    unsigned short* sVf1 = (unsigned short*)(smem + 40960);   // tile B: V
    unsigned short* sWa  = (unsigned short*)(smem + 49152);   // W ping / attn-A ping / Wfc
    unsigned short* sWb  = (unsigned short*)(smem + 57344);   // W pong / attn-B ping
    unsigned short* sWc  = (unsigned short*)(smem + 65536);   // attn-A pong
    unsigned short* sWd  = (unsigned short*)(smem + 73728);   // attn-B pong

    const int bn0  = blockIdx.x * 2;
    const int tid  = threadIdx.x;
    const int w    = tid >> 6;
    const int lane = tid & 63;
    const int quad = lane >> 4;
    const int l16  = lane & 15;
    const size_t base_a = (size_t)bn0 * 4096;
    const size_t base_b = base_a + 4096;

    // S^T lane geometry: q = nt*16 + l16, k = w*16 + quad*4 + r
    const int soff0 = l16 * 64 + w * 16 + quad * 4;
    const int xoff  = (w * 16 + l16) * 64 + quad * 8;

    bool bma[4], bmb[4];
#pragma unroll
    for (int nt = 0; nt < 4; ++nt) {
        bma[nt] = maskp[bn0 * 64 + nt * 16 + l16] > 0.5f;
        bmb[nt] = maskp[(bn0 + 1) * 64 + nt * 16 + l16] > 0.5f;
    }

    // res^T head-0 prefetch, both tiles (lands under projections)
    f32x4 rAa[4], rAb[4];
    {
        const float* ra = res + (((size_t)(bn0 * 4)) << 12) + soff0;
        const float* rb = res + (((size_t)((bn0 + 1) * 4)) << 12) + soff0;
#pragma unroll
        for (int nt = 0; nt < 4; ++nt) {
            rAa[nt] = *reinterpret_cast<const f32x4*>(ra + nt * 1024);
            rAb[nt] = *reinterpret_cast<const f32x4*>(rb + nt * 1024);
        }
    }

    // ---------------- Projections (pipelined, W shared by both tiles) ----------------
    float4 wv[4], xa[4], xb[4], ya[4], yb[4];
    loadW(Wq, wv, tid);
    {
        const float* pa = Xq + base_a + xoff;
        const float* pb = Xq + base_b + xoff;
        xa[0] = *(const float4*)(pa);      xa[1] = *(const float4*)(pa + 4);
        xa[2] = *(const float4*)(pa + 32); xa[3] = *(const float4*)(pa + 36);
        xb[0] = *(const float4*)(pb);      xb[1] = *(const float4*)(pb + 4);
        xb[2] = *(const float4*)(pb + 32); xb[3] = *(const float4*)(pb + 36);
    }
    writeW(wv, sWa, tid);
    bar_lds();                                           // B1

    // pj0 (Q): issue pj1's W+X, compute both tiles
    loadW(Wk, wv, tid);
    {
        const float* pa = Xk + base_a + xoff;
        const float* pb = Xk + base_b + xoff;
        ya[0] = *(const float4*)(pa);      ya[1] = *(const float4*)(pa + 4);
        ya[2] = *(const float4*)(pa + 32); ya[3] = *(const float4*)(pa + 36);
        yb[0] = *(const float4*)(pb);      yb[1] = *(const float4*)(pb + 4);
        yb[2] = *(const float4*)(pb + 32); yb[3] = *(const float4*)(pb + 36);
    }
    proj_tile<0>(xa, sWa, sQf0, sKf0, sVf0, w, lane, quad, l16);
    proj_tile<0>(xb, sWa, sQf1, sKf1, sVf1, w, lane, quad, l16);
    writeW(wv, sWb, tid);
    bar_lds();                                           // B2

    // pj1 (K): issue pj2's W+X
    loadW(Wv, wv, tid);
    {
        const float* pa = Xv + base_a + xoff;
        const float* pb = Xv + base_b + xoff;
        xa[0] = *(const float4*)(pa);      xa[1] = *(const float4*)(pa + 4);
        xa[2] = *(const float4*)(pa + 32); xa[3] = *(const float4*)(pa + 36);
        xb[0] = *(const float4*)(pb);      xb[1] = *(const float4*)(pb + 4);
        xb[2] = *(const float4*)(pb + 32); xb[3] = *(const float4*)(pb + 36);
    }
    proj_tile<1>(ya, sWb, sQf0, sKf0, sVf0, w, lane, quad, l16);
    proj_tile<1>(yb, sWb, sQf1, sKf1, sVf1, w, lane, quad, l16);
    writeW(wv, sWa, tid);
    bar_lds();                                           // B3

    // pj2 (V)
    proj_tile<2>(xa, sWa, sQf0, sKf0, sVf0, w, lane, quad, l16);
    proj_tile<2>(xb, sWa, sQf1, sKf1, sVf1, w, lane, quad, l16);
    bar_lds();                                           // B4: all frags visible

    // ---------------- Attention (dual-stream, 1 barrier/head) ----------------
    f32x4 ctxa[4], ctxb[4];
#pragma unroll
    for (int h = 0; h < 4; ++h) { ctxa[h] = {0.f,0.f,0.f,0.f}; ctxb[h] = {0.f,0.f,0.f,0.f}; }

    float4 wfc[4];
#pragma unroll
    for (int h = 0; h < 4; ++h) {
        const size_t sba = ((size_t)(bn0 * 4 + h)) << 12;
        const size_t sbb = sba + 16384;          // (bn0+1)*4+h
        unsigned short* bufA = (h & 1) ? sWc : sWa;
        unsigned short* bufB = (h & 1) ? sWd : sWb;

        attn_tile(sKf0, sQf0, bufA, rAa, bma, scores_out + sba + soff0, h, w, lane, quad, l16);
        attn_tile(sKf1, sQf1, bufB, rAb, bmb, scores_out + sbb + soff0, h, w, lane, quad, l16);
        bar_lds();     // publishes both tiles' frags; prefetches survive

        if (h < 3) {   // next head's res^T for both tiles (post-barrier issue)
            const float* ra = res + sba + 4096 + soff0;
            const float* rb = res + sbb + 4096 + soff0;
#pragma unroll
            for (int nt = 0; nt < 4; ++nt) {
                rAa[nt] = *reinterpret_cast<const f32x4*>(ra + nt * 1024);
                rAb[nt] = *reinterpret_cast<const f32x4*>(rb + nt * 1024);
            }
        } else {
            loadW(Wfc, wfc, tid);               // fc operand issue-early
        }

        // PV both tiles (wave w owns q rows w*16..+15)
#pragma unroll
        for (int ki = 0; ki < 2; ++ki) {
            s16x8 apA = ldfrag(bufA + (swz((w * 2 + ki) * 64 + lane) << 3));
            s16x8 bvA = ldfrag(sVf0 + (swz((h * 2 + ki) * 64 + lane) << 3));
            ctxa[h] = __builtin_amdgcn_mfma_f32_16x16x32_bf16(apA, bvA, ctxa[h], 0, 0, 0);
            s16x8 apB = ldfrag(bufB + (swz((w * 2 + ki) * 64 + lane) << 3));
            s16x8 bvB = ldfrag(sVf1 + (swz((h * 2 + ki) * 64 + lane) << 3));
            ctxb[h] = __builtin_amdgcn_mfma_f32_16x16x32_bf16(apB, bvB, ctxb[h], 0, 0, 0);
        }
        // no post-PV barrier: ping-pong; barrier h+1 orders buf reuse at h+2
    }
    bar_lds();         // attention LDS reads done; sKf*/sWa reusable

    // ---------------- fc + residual + layernorm (both tiles) ----------------
    const int toff = (w * 16 + quad * 4) * 64 + l16;
#pragma unroll
    for (int hh = 0; hh < 4; ++hh) {
        int c    = hh * 16 + l16;
        int rowb = (w * 2 + (c >> 5)) * 64 + (((c >> 3) & 3) << 4) + quad * 4;
#pragma unroll
        for (int r = 0; r < 4; ++r) {
            sKf0[(swz(rowb + r) << 3) + (c & 7)] = f2bf(ctxa[hh][r]);
            sKf1[(swz(rowb + r) << 3) + (c & 7)] = f2bf(ctxb[hh][r]);
        }
    }
    writeW(wfc, sWa, tid);
    float xra[4][4], xrb[4][4], scl[4], bia[4];
    {
        const float* pa = Xq + base_a + toff;
        const float* pb = Xq + base_b + toff;
#pragma unroll
        for (int nt = 0; nt < 4; ++nt) {
#pragma unroll
            for (int r = 0; r < 4; ++r) {
                xra[nt][r] = pa[r * 64 + nt * 16];
                xrb[nt][r] = pb[r * 64 + nt * 16];
            }
            scl[nt] = lnS[nt * 16 + l16];
            bia[nt] = lnB[nt * 16 + l16];
        }
    }
    bar_lds();

#pragma unroll
    for (int t = 0; t < 2; ++t) {
        const unsigned short* sA = (t == 0) ? sKf0 : sKf1;
        const size_t baseo = (t == 0) ? base_a : base_b;
        f32x4 oacc[4];
        {
            s16x8 a0 = ldfrag(sA + (swz((w * 2 + 0) * 64 + lane) << 3));
            s16x8 a1 = ldfrag(sA + (swz((w * 2 + 1) * 64 + lane) << 3));
#pragma unroll
            for (int nt = 0; nt < 4; ++nt) {
                f32x4 a = {0.f, 0.f, 0.f, 0.f};
                s16x8 b0 = ldfrag(sWa + (swz((nt * 2 + 0) * 64 + lane) << 3));
                s16x8 b1 = ldfrag(sWa + (swz((nt * 2 + 1) * 64 + lane) << 3));
                a = __builtin_amdgcn_mfma_f32_16x16x32_bf16(a0, b0, a, 0, 0, 0);
                a = __builtin_amdgcn_mfma_f32_16x16x32_bf16(a1, b1, a, 0, 0, 0);
                oacc[nt] = a;
            }
        }
#pragma unroll
        for (int r = 0; r < 4; ++r) {
            float px[4], sum = 0.f, sq = 0.f;
#pragma unroll
            for (int nt = 0; nt < 4; ++nt) {
                float x = oacc[nt][r] + ((t == 0) ? xra[nt][r] : xrb[nt][r]);
                px[nt] = x; sum += x; sq += x * x;
            }
#pragma unroll
            for (int m = 1; m <= 8; m <<= 1) {
                sum += __shfl_xor(sum, m, 64);
                sq  += __shfl_xor(sq,  m, 64);
            }
            float mu   = sum * 0.015625f;
            float var  = sq * 0.015625f - mu * mu;
            float rstd = rsqrtf(var + 1e-5f);
#pragma unroll
            for (int nt = 0; nt < 4; ++nt) {
                out[baseo + toff + r * 64 + nt * 16] = (px[nt] - mu) * rstd * scl[nt] + bia[nt];
            }
        }
    }
}

extern "C" void kernel_launch(void* const* d_in, const int* in_sizes, int n_in,
                              void* d_out, int out_size, void* d_ws, size_t ws_size,
                              hipStream_t stream) {
    const float* Xq   = (const float*)d_in[0];
    const float* Xk   = (const float*)d_in[1];
    const float* Xv   = (const float*)d_in[2];
    const float* msk  = (const float*)d_in[3];
    const float* res  = (const float*)d_in[4];
    const float* Wq   = (const float*)d_in[5];
    const float* Wk   = (const float*)d_in[6];
    const float* Wv   = (const float*)d_in[7];
    const float* Wfc  = (const float*)d_in[8];
    const float* lnS  = (const float*)d_in[9];
    const float* lnB  = (const float*)d_in[10];
    float* out    = (float*)d_out;
    float* scores = out + OUT_ELEMS;
    mta_kernel<<<NB2, 256, 0, stream>>>(Xq, Xk, Xv, msk, res, Wq, Wk, Wv, Wfc,
                                        lnS, lnB, out, scores);
}